// Round 7
// baseline (198.950 us; speedup 1.0000x reference)
//
#include <hip/hip_runtime.h>
#include <hip/hip_bf16.h>
#include <hip/hip_fp16.h>
#include <math.h>

#define BATCH 32
#define INC 1024
#define MIDC 256
#define SC 256
#define HW 784
#define ROWS 25088   // BATCH*HW
#define KSEL 196     // int(0.25 * 784)

typedef _Float16 f16;
typedef __attribute__((ext_vector_type(8))) _Float16 hfrag;  // 8 fp16 (4 VGPRs)
typedef __attribute__((ext_vector_type(4))) float f4;        // 4 fp32 acc

struct alignas(8) h4s { f16 x, y, z, w; };

__device__ inline float stanh_fast(float p) {
    // 1.7159*tanh(2p/3) = 1.7159*(1 - 2/(exp(4p/3)+1))
    float e = __expf(1.33333333f * p);
    return 1.7159f * (1.0f - 2.0f / (e + 1.0f));
}

// ---------------- fp32 -> fp16 weight convert (layout preserved) -----------
__global__ __launch_bounds__(256) void cvt_f16(const float* __restrict__ src,
                                               f16* __restrict__ dst, int n4) {
    int i = blockIdx.x * 256 + threadIdx.x;
    if (i >= n4) return;
    float4 v = ((const float4*)src)[i];
    h4s h = { (f16)v.x, (f16)v.y, (f16)v.z, (f16)v.w };
    ((h4s*)dst)[i] = h;
}

// ---------------- transpose x[b][c][n] -> xt[b][n][c] as fp16 --------------
__global__ __launch_bounds__(256) void prep_x(const float* __restrict__ x,
                                              f16* __restrict__ xh) {
    int b = blockIdx.z, c0 = blockIdx.y * 32, n0 = blockIdx.x * 32;
    __shared__ float tile[32][33];
    int t = threadIdx.x;
    int r = t >> 3, cg = (t & 7) * 4;
    if (n0 + cg + 3 < HW) {
        float4 v = *(const float4*)(x + (size_t)(b * INC + c0 + r) * HW + n0 + cg);
        tile[r][cg + 0] = v.x; tile[r][cg + 1] = v.y;
        tile[r][cg + 2] = v.z; tile[r][cg + 3] = v.w;
    }
    __syncthreads();
    int rn = t >> 3, cg2 = (t & 7) * 4;
    int n = n0 + rn;
    if (n < HW) {
        h4s h = { (f16)tile[cg2 + 0][rn], (f16)tile[cg2 + 1][rn],
                  (f16)tile[cg2 + 2][rn], (f16)tile[cg2 + 3][rn] };
        *(h4s*)(xh + ((size_t)b * HW + n) * INC + c0 + cg2) = h;
    }
}

// ---------------- u[b][m] = Wq_b[m] + Uq·s ---------------------------------
__global__ __launch_bounds__(256) void calc_u(const float* __restrict__ s,
                                              const float* __restrict__ Uq_w,
                                              const float* __restrict__ Wq_b,
                                              float* __restrict__ u) {
    __shared__ float ssh[SC];
    int b = blockIdx.x, m = threadIdx.x;
    ssh[m] = s[b * SC + m];
    __syncthreads();
    float acc = Wq_b[m];
    const float* uq = Uq_w + (size_t)m * SC;
    #pragma unroll 8
    for (int i = 0; i < SC; ++i) acc += ssh[i] * uq[i];
    u[b * MIDC + m] = acc;
}

// ---------------- GEMM1: sig_t[R][m] = stanh(Wq·xt[R] + u[R/784][m]) -------
__global__ __launch_bounds__(256) void gemm1_mfma(
    const f16* __restrict__ A,   // Wq [256][1024]
    const f16* __restrict__ B,   // xt [25088][1024]
    const float* __restrict__ u,
    f16* __restrict__ S) {       // sig [25088][256]
    const int R0 = blockIdx.x * 64;
    const int M0 = blockIdx.y * 128;
    __shared__ f16 Asm[128][40];
    __shared__ f16 Bsm[64][40];
    const int t = threadIdx.x;
    const int lane = t & 63, w = t >> 6;
    const int wc = (w >> 1) * 64;
    const int wr = (w & 1) * 32;
    const int ln = lane & 15, kg = lane >> 4;

    const int ar0 = t >> 2, ar1 = ar0 + 64;
    const int akc = (t & 3) * 8;
    const size_t aoff0 = (size_t)(M0 + ar0) * INC + akc;
    const size_t aoff1 = (size_t)(M0 + ar1) * INC + akc;
    const size_t boff  = (size_t)(R0 + ar0) * INC + akc;

    f4 acc[4][2];
    const f4 zero = {0.f, 0.f, 0.f, 0.f};
    #pragma unroll
    for (int i = 0; i < 4; ++i) { acc[i][0] = zero; acc[i][1] = zero; }

    hfrag rA0, rA1, rB;
    #define G1_LOAD(K0)                                   \
        rA0 = *(const hfrag*)(A + aoff0 + (K0));          \
        rA1 = *(const hfrag*)(A + aoff1 + (K0));          \
        rB  = *(const hfrag*)(B + boff  + (K0));

    G1_LOAD(0)
    for (int k0 = 0; k0 < INC; k0 += 32) {
        *(hfrag*)&Asm[ar0][akc] = rA0;
        *(hfrag*)&Asm[ar1][akc] = rA1;
        *(hfrag*)&Bsm[ar0][akc] = rB;
        __syncthreads();
        if (k0 + 32 < INC) { G1_LOAD(k0 + 32) }
        hfrag b0 = *(const hfrag*)&Bsm[wr + ln][kg * 8];
        hfrag b1 = *(const hfrag*)&Bsm[wr + 16 + ln][kg * 8];
        #pragma unroll
        for (int mi = 0; mi < 4; ++mi) {
            hfrag a = *(const hfrag*)&Asm[wc + mi * 16 + ln][kg * 8];
            acc[mi][0] = __builtin_amdgcn_mfma_f32_16x16x32_f16(a, b0, acc[mi][0], 0, 0, 0);
            acc[mi][1] = __builtin_amdgcn_mfma_f32_16x16x32_f16(a, b1, acc[mi][1], 0, 0, 0);
        }
        __syncthreads();
    }
    #undef G1_LOAD

    #pragma unroll
    for (int ni = 0; ni < 2; ++ni) {
        int R = R0 + wr + ni * 16 + ln;
        int b = R / HW;
        #pragma unroll
        for (int mi = 0; mi < 4; ++mi) {
            int mb = M0 + wc + mi * 16 + kg * 4;
            float uv[4];
            *(float4*)uv = *(const float4*)(u + b * MIDC + mb);
            h4s hv;
            hv.x = (f16)stanh_fast(acc[mi][ni][0] + uv[0]);
            hv.y = (f16)stanh_fast(acc[mi][ni][1] + uv[1]);
            hv.z = (f16)stanh_fast(acc[mi][ni][2] + uv[2]);
            hv.w = (f16)stanh_fast(acc[mi][ni][3] + uv[3]);
            *(h4s*)(S + (size_t)R * MIDC + mb) = hv;
        }
    }
}

// ---------------- GEMM2: alpha[b][c][n] = Ww·sig_t[R] + wb, R=(b,n) --------
__global__ __launch_bounds__(256) void gemm2_mfma(
    const f16* __restrict__ A,   // Ww [1024][256]
    const f16* __restrict__ B,   // sig [25088][256]
    const float* __restrict__ wb,
    float* __restrict__ aout) {
    const int R0 = blockIdx.x * 128;
    const int C0 = blockIdx.y * 128;
    __shared__ f16 Asm[128][40];
    __shared__ f16 Bsm[128][40];
    const int t = threadIdx.x;
    const int lane = t & 63, w = t >> 6;
    const int wc = (w >> 1) * 64;
    const int wr = (w & 1) * 64;
    const int ln = lane & 15, kg = lane >> 4;

    const int r0 = t >> 2, r1 = r0 + 64;
    const int kc = (t & 3) * 8;
    const size_t aoff0 = (size_t)(C0 + r0) * MIDC + kc;
    const size_t aoff1 = (size_t)(C0 + r1) * MIDC + kc;
    const size_t boff0 = (size_t)(R0 + r0) * MIDC + kc;
    const size_t boff1 = (size_t)(R0 + r1) * MIDC + kc;

    f4 acc[4][4];
    const f4 zero = {0.f, 0.f, 0.f, 0.f};
    #pragma unroll
    for (int i = 0; i < 4; ++i)
        #pragma unroll
        for (int j = 0; j < 4; ++j) acc[i][j] = zero;

    hfrag rA0, rA1, rB0, rB1;
    #define G2_LOAD(K0)                                   \
        rA0 = *(const hfrag*)(A + aoff0 + (K0));          \
        rA1 = *(const hfrag*)(A + aoff1 + (K0));          \
        rB0 = *(const hfrag*)(B + boff0 + (K0));          \
        rB1 = *(const hfrag*)(B + boff1 + (K0));

    G2_LOAD(0)
    for (int k0 = 0; k0 < MIDC; k0 += 32) {
        *(hfrag*)&Asm[r0][kc] = rA0;
        *(hfrag*)&Asm[r1][kc] = rA1;
        *(hfrag*)&Bsm[r0][kc] = rB0;
        *(hfrag*)&Bsm[r1][kc] = rB1;
        __syncthreads();
        if (k0 + 32 < MIDC) { G2_LOAD(k0 + 32) }
        hfrag bh[4];
        #pragma unroll
        for (int ni = 0; ni < 4; ++ni)
            bh[ni] = *(const hfrag*)&Bsm[wr + ni * 16 + ln][kg * 8];
        #pragma unroll
        for (int mi = 0; mi < 4; ++mi) {
            hfrag a = *(const hfrag*)&Asm[wc + mi * 16 + ln][kg * 8];
            #pragma unroll
            for (int ni = 0; ni < 4; ++ni)
                acc[mi][ni] = __builtin_amdgcn_mfma_f32_16x16x32_f16(a, bh[ni], acc[mi][ni], 0, 0, 0);
        }
        __syncthreads();
    }
    #undef G2_LOAD

    #pragma unroll
    for (int ni = 0; ni < 4; ++ni) {
        int R = R0 + wr + ni * 16 + ln;
        int b = R / HW;
        int n = R - b * HW;
        float* arow = aout + (size_t)b * INC * HW + n;
        #pragma unroll
        for (int mi = 0; mi < 4; ++mi) {
            int cb = C0 + wc + mi * 16 + kg * 4;
            float wv[4];
            *(float4*)wv = *(const float4*)(wb + cb);
            #pragma unroll
            for (int r = 0; r < 4; ++r)
                arow[(size_t)(cb + r) * HW] = acc[mi][ni][r] + wv[r];
        }
    }
}

// ---------------- per-(b,c) row: linear-bin select v4 -----------------------
// Exact k-th-largest via iterative 64-bin LINEAR partition over [umin,umax]
// of the monotone uint keys. Gaussian-ish data spreads evenly over linear
// bins (max ~9 atomics/bin/subgroup vs ~68 for the exponent-byte radix).
// Mapping key->bin is monotone (uint->float cvt, RN mul, trunc all monotone),
// so bin boundaries partition the key space exactly; threshold is recovered
// as max/min of candidate KEYS (bit-exact). min->bin0, max->bin63 each round
// guarantees strict candidate shrink -> terminates (typ. 2 rounds).
__global__ __launch_bounds__(256) void topk_softmax_reduce(const float* __restrict__ x,
                                                           float* __restrict__ out) {
    const int wid  = threadIdx.x >> 6;
    const int lane = threadIdx.x & 63;
    const int row  = blockIdx.x * 4 + wid;
    float* arow = out + BATCH * INC + (size_t)row * HW;
    const float* xrow = x + (size_t)row * HW;

    __shared__ int hist[4][4][72];   // [wave][subgroup][bin(+8 pad -> bank offset 8g)]
    int* hp0 = &hist[wid][0][0];
    const int g = lane >> 4;

    const bool has3 = (lane < 4);
    float4 v4[4];
    uint32_t key[16];

    {   // vectorized load of the row (196 float4 chunks)
        const float4* ap = (const float4*)arow;
        v4[0] = ap[lane];
        v4[1] = ap[lane + 64];
        v4[2] = ap[lane + 128];
        v4[3] = has3 ? ap[192 + lane] : make_float4(0.f, 0.f, 0.f, 0.f);
    }
    const float* vv = (const float*)v4;
    #pragma unroll
    for (int i = 0; i < 16; ++i) {
        uint32_t uu = __float_as_uint(vv[i]);
        key[i] = (uu & 0x80000000u) ? ~uu : (uu | 0x80000000u);
    }

    uint32_t cand = has3 ? 0xFFFFu : 0x0FFFu;   // valid slots (784 = 12*64 + 4*4)
    int kk = KSEL;
    uint32_t thkey = 0;

    for (int iter = 0; iter < 16; ++iter) {
        // min/max over candidate keys
        uint32_t umin = 0xFFFFFFFFu, umax = 0u;
        #pragma unroll
        for (int i = 0; i < 16; ++i) {
            if ((cand >> i) & 1) {
                uint32_t kc = key[i];
                umin = umin < kc ? umin : kc;
                umax = umax > kc ? umax : kc;
            }
        }
        #pragma unroll
        for (int off = 32; off; off >>= 1) {
            uint32_t omn = (uint32_t)__shfl_xor((int)umin, off, 64);
            uint32_t omx = (uint32_t)__shfl_xor((int)umax, off, 64);
            umin = umin < omn ? umin : omn;
            umax = umax > omx ? umax : omx;
        }
        thkey = umin;                       // safe fallback if cap hits
        if (umin == umax) break;            // all candidates tie
        const float scale = 63.999f / (float)(umax - umin);

        // zero + fill per-subgroup histograms (barrier-free: per-wave LDS)
        const int4 z4 = {0, 0, 0, 0};
        ((int4*)hp0)[lane] = z4;
        if (lane < 8) ((int4*)hp0)[64 + lane] = z4;
        #pragma unroll
        for (int i = 0; i < 16; ++i) {
            if ((cand >> i) & 1) {
                int bn = (int)((float)(key[i] - umin) * scale);
                atomicAdd(&hist[wid][g][bn], 1);
            }
        }

        // lane owns bin=lane; sum subgroups, suffix-scan for rank-from-top
        int h = hist[wid][0][lane] + hist[wid][1][lane]
              + hist[wid][2][lane] + hist[wid][3][lane];
        int suf = h;
        #pragma unroll
        for (int off = 1; off < 64; off <<= 1) {
            int o = __shfl_down(suf, off, 64);
            suf += (lane + off < 64) ? o : 0;
        }
        int cgt = suf - h;                  // count in bins above mine
        bool hit = (cgt < kk && kk <= cgt + h);
        unsigned long long m = __ballot(hit);
        int bsel = (int)__ffsll((long long)m) - 1;   // exactly one lane hits
        int cg = __shfl(cgt, bsel, 64);
        int hs = __shfl(h,   bsel, 64);
        kk -= cg;

        bool exit_max = (kk == 1), exit_min = (kk == hs);
        if (exit_max | exit_min) {
            uint32_t r = exit_max ? 0u : 0xFFFFFFFFu;
            #pragma unroll
            for (int i = 0; i < 16; ++i) {
                if ((cand >> i) & 1) {
                    int bn = (int)((float)(key[i] - umin) * scale);
                    if (bn == bsel)
                        r = exit_max ? (r > key[i] ? r : key[i])
                                     : (r < key[i] ? r : key[i]);
                }
            }
            #pragma unroll
            for (int off = 32; off; off >>= 1) {
                uint32_t o = (uint32_t)__shfl_xor((int)r, off, 64);
                r = exit_max ? (r > o ? r : o) : (r < o ? r : o);
            }
            thkey = r;
            break;
        }
        // narrow candidates to selected bin
        uint32_t nc = 0;
        #pragma unroll
        for (int i = 0; i < 16; ++i) {
            if ((cand >> i) & 1) {
                int bn = (int)((float)(key[i] - umin) * scale);
                if (bn == bsel) nc |= (1u << i);
            }
        }
        cand = nc;
    }

    uint32_t tu = (thkey & 0x80000000u) ? (thkey ^ 0x80000000u) : ~thkey;
    const float th = __uint_as_float(tu);

    // mask + max
    float* vw = (float*)v4;
    float mx = -INFINITY;
    #pragma unroll
    for (int i = 0; i < 16; ++i) {
        bool ok = (i < 12) | has3;
        float f = vw[i];
        f = (f < th) ? 0.0f : f;
        vw[i] = f;
        if (ok) mx = fmaxf(mx, f);
    }
    #pragma unroll
    for (int off = 32; off; off >>= 1) mx = fmaxf(mx, __shfl_xor(mx, off, 64));

    // exp + sum
    float sum = 0.f;
    #pragma unroll
    for (int i = 0; i < 16; ++i) {
        bool ok = (i < 12) | has3;
        float e = __expf(vw[i] - mx);
        vw[i] = e;
        sum += ok ? e : 0.f;
    }
    #pragma unroll
    for (int off = 32; off; off >>= 1) sum += __shfl_xor(sum, off, 64);
    float inv = 1.0f / sum;

    // normalize + store atten + weighted reduce against x
    float dot = 0.f;
    {
        float4* ap = (float4*)arow;
        const float4* xp = (const float4*)xrow;
        #pragma unroll
        for (int ci = 0; ci < 4; ++ci) {
            if (ci == 3 && !has3) break;
            int chunk = (ci < 3) ? (lane + 64 * ci) : (192 + lane);
            float4 a;
            a.x = vw[ci * 4 + 0] * inv;
            a.y = vw[ci * 4 + 1] * inv;
            a.z = vw[ci * 4 + 2] * inv;
            a.w = vw[ci * 4 + 3] * inv;
            ap[chunk] = a;
            float4 xl = xp[chunk];
            dot += xl.x * a.x + xl.y * a.y + xl.z * a.z + xl.w * a.w;
        }
    }
    #pragma unroll
    for (int off = 32; off; off >>= 1) dot += __shfl_xor(dot, off, 64);
    if (lane == 0) out[row] = dot;
}

extern "C" void kernel_launch(void* const* d_in, const int* in_sizes, int n_in,
                              void* d_out, int out_size, void* d_ws, size_t ws_size,
                              hipStream_t stream) {
    const float* x    = (const float*)d_in[0];
    const float* s    = (const float*)d_in[1];
    const float* Wq_w = (const float*)d_in[2];
    const float* Wq_b = (const float*)d_in[3];
    const float* Uq_w = (const float*)d_in[4];
    const float* w_w  = (const float*)d_in[5];
    const float* w_b  = (const float*)d_in[6];
    float* out = (float*)d_out;

    f16* xt   = (f16*)d_ws;                                   // [25088][1024]
    f16* sig  = xt + (size_t)ROWS * INC;                      // [25088][256]
    f16* wq_h = sig + (size_t)ROWS * MIDC;                    // [256][1024]
    f16* ww_h = wq_h + MIDC * INC;                            // [1024][256]
    float* u  = (float*)(ww_h + INC * MIDC);                  // [32][256]
    float* alpha = out + BATCH * INC;                         // staged in atten slot

    cvt_f16<<<256, 256, 0, stream>>>(Wq_w, wq_h, MIDC * INC / 4);
    cvt_f16<<<256, 256, 0, stream>>>(w_w, ww_h, INC * MIDC / 4);
    prep_x<<<dim3(25, 32, 32), 256, 0, stream>>>(x, xt);
    calc_u<<<BATCH, 256, 0, stream>>>(s, Uq_w, Wq_b, u);
    gemm1_mfma<<<dim3(ROWS / 64, 2), 256, 0, stream>>>(wq_h, xt, u, sig);
    gemm2_mfma<<<dim3(ROWS / 128, 8), 256, 0, stream>>>(ww_h, sig, w_b, alpha);
    topk_softmax_reduce<<<BATCH * INC / 4, 256, 0, stream>>>(x, out);
}